// Round 20
// baseline (314.446 us; speedup 1.0000x reference)
//
#include <hip/hip_runtime.h>

#define B_N 8192
#define D_N 512
#define K_N 64
#define H_N 256
#define SC  4608   // K*K + D
#define NT  512

typedef __attribute__((ext_vector_type(8))) short short8;
typedef __attribute__((ext_vector_type(4))) short short4v;
typedef __attribute__((ext_vector_type(4))) float f32x4;

__device__ __forceinline__ unsigned short f2bf(float f) {
  unsigned int u = __builtin_bit_cast(unsigned int, f);
  u += 0x7fff + ((u >> 16) & 1);      // RNE
  return (unsigned short)(u >> 16);
}
__device__ __forceinline__ float bf2f(unsigned short h) {
  unsigned int u = ((unsigned int)h) << 16;
  return __builtin_bit_cast(float, u);
}

// ---- weights region (bf16 elements), per layer ----
// W1T [256][512]  @ 0        (W1T[n][k] = W1[k][n])
// UT  [ 64][512]  @ 131072
// W2C [chunks]    @ 163840   : 4KB chunks, chunk id c = (kg*2+th)*4 + nq:
//                  elem = c*2048 + kk*512 + lane*8 + te   (lane = g*16+l15)
//                  value = W2[t][512 + 64*kg + nq*16 + l15],
//                  t = th*128 + kk*32 + g*8 + te
// W2bT[ 512][256] @ 1212416  (W2bT[n][t] = W2[t][n])
// VT  [ 512][ 64] @ 1343488
#define L_ELEMS 1376256

// ---- ws byte offsets (as round 15, proven ws_size >= WS_NEED) ----
#define OFF_H1  8257536u    // h1  bf16 [8192][256]
#define OFF_TMP 14548992u   // tmp f32  [8192][64]
#define OFF_X   16646144u   // x   bf16 [8192][512]

struct PrepParams {
  const float* W1[3]; const float* U[3]; const float* W2[3]; const float* V[3];
  short* ws;
};

__global__ __launch_bounds__(256) void prep_weights(PrepParams p) {
  const int y = blockIdx.y;           // 0..14
  const int l = y / 5, m = y - 5 * l;
  short* wsl = p.ws + (size_t)l * L_ELEMS;
  if (m == 2) {                       // W2C chunked layout
    const float* in = p.W2[l];
    short* out = wsl + 163840;
    const long total = 1048576;
    for (long e = (long)blockIdx.x * 256 + threadIdx.x; e < total;
         e += (long)gridDim.x * 256) {
      const int te   = (int)(e & 7);
      const int lane = (int)((e >> 3) & 63);
      const int kk   = (int)((e >> 9) & 3);
      const int nq   = (int)((e >> 11) & 3);
      const int h2   = (int)((e >> 13) & 1);
      const int kg   = (int)(e >> 14);
      const int g    = lane >> 4;
      const int l15  = lane & 15;
      const int t    = h2 * 128 + kk * 32 + g * 8 + te;
      out[e] = (short)f2bf(in[(size_t)t * SC + 512 + 64 * kg + nq * 16 + l15]);
    }
    return;
  }
  const float* in; short* out; int K, istride, ioff, kshift;
  switch (m) {
    case 0: in = p.W1[l]; out = wsl;           K = 512; istride = 256;  ioff = 0; kshift = 9; break;
    case 1: in = p.U[l];  out = wsl + 131072;  K = 512; istride = 64;   ioff = 0; kshift = 9; break;
    case 3: in = p.W2[l]; out = wsl + 1212416; K = 256; istride = 4608; ioff = 0; kshift = 8; break;
    default:in = p.V[l];  out = wsl + 1343488; K = 64;  istride = 512;  ioff = 0; kshift = 6; break;
  }
  const long total = (long)K * ((m == 0) ? 256 : (m == 1) ? 64 : 512);
  for (long e = (long)blockIdx.x * 256 + threadIdx.x; e < total;
       e += (long)gridDim.x * 256) {
    const int k = (int)(e & (K - 1));
    const int n = (int)(e >> kshift);
    out[e] = (short)f2bf(in[(size_t)k * istride + ioff + n]);
  }
}

// stage one 4KB chunk into a wave-private ring slot (4 x 16B per lane)
__device__ __forceinline__ void stage_chunk(const short* W2p, short* slotp,
                                            int cglob, int nq, int lane) {
  const short* gp = W2p + (((size_t)cglob * 4 + nq) << 11) + (lane << 3);
#pragma unroll
  for (int i = 0; i < 4; ++i) {
    __builtin_amdgcn_global_load_lds(
        (const __attribute__((address_space(1))) void*)(gp + (i << 9)),
        (__attribute__((address_space(3))) void*)(slotp + (i << 9)), 16, 0, 0);
  }
}

// ============ KC: block (rt, jh) = 64 rows x j-half of the einsum ==========
// A/B for 64 rows (h1/h in LDS; h1 -> global from jh==0 blocks),
// C streams only this block's j-half of W2S (1 MB) via r14's proven
// private-ring pipeline; each chunk feeds 2 aH register sets (32 rows/wave).
struct CParams {
  const float* xf;   // layer0 input (f32) or nullptr
  const short* xb;   // layers 1,2 input (bf16)
  const short* wsl;
  const float* b1;
  const float* b2;
  short* h1w;
  float* tmpf;       // [8192][64] f32, disjoint writes (no atomics)
};

__global__ __launch_bounds__(NT, 1) void apg_c(CParams p) {
  __shared__ __attribute__((aligned(16))) short ring[8][3][2048]; // 96 KB
  __shared__ short h1s[64][264];    // 33.8 KB
  __shared__ float hs[64][68];      // 17.4 KB (pad 68: conflict-free)
  short (*xs)[520] = (short (*)[520]) & ring[0][0][0];  // 66.6 KB, aliases ring

  const int tid  = threadIdx.x;
  const int w    = tid >> 6;         // wave 0..7
  const int lane = tid & 63;
  const int l15  = tid & 15;
  const int g    = (tid & 63) >> 4;  // 0..3
  const int koff = g * 8;
  const int mh   = w >> 2;           // row-half of 64 (32 rows)
  const int kh   = (w >> 1) & 1;     // k-half
  const int nq2  = w & 1;            // j-slice within this block's half
  const int rt   = blockIdx.x >> 1;
  const int jh   = blockIdx.x & 1;   // j-half owned by this block
  const int nqg  = jh * 2 + nq2;     // global 16-j slice 0..3
  const int R0   = rt * 64;

  // ---- load x tile (64 rows) -> bf16 LDS ----
  if (p.xf) {
    const float4* xg = (const float4*)(p.xf + (size_t)R0 * D_N);
    for (int i = tid; i < 64 * D_N / 4; i += NT) {
      float4 v = xg[i];
      const int r = i >> 7, c = (i & 127) << 2;
      short4v s4 = { (short)f2bf(v.x), (short)f2bf(v.y), (short)f2bf(v.z), (short)f2bf(v.w) };
      *(short4v*)&xs[r][c] = s4;
    }
  } else {
    const short8* xg = (const short8*)(p.xb + (size_t)R0 * D_N);
    for (int i = tid; i < 64 * D_N / 8; i += NT) {
      short8 v = xg[i];
      const int r = i >> 6, c = (i & 63) << 3;
      *(short8*)&xs[r][c] = v;
    }
  }
  __syncthreads();

  // ---- stages A+B: h1 = relu(x@W1+b1), h = x@U; 64 rows, 2 row-sets/wave.
  //      cols: wave (kh,nq2) -> A range 64*(kh*2+nq2), B frag 16*(kh*2+nq2).
  //      Extra rows are ~free: A/B are weight-stream-bound per block. ----
  {
    const int cq = kh * 2 + nq2;
    for (int rs = 0; rs < 2; ++rs) {
      const int rb = mh * 32 + rs * 16;
      short8 aX[16];
#pragma unroll
      for (int kk = 0; kk < 16; ++kk)
        aX[kk] = *(const short8*)&xs[rb + l15][kk * 32 + koff];
      for (int nf = 0; nf < 4; ++nf) {
        const int n0 = (cq << 6) + (nf << 4);
        const short* pb = p.wsl + ((size_t)(n0 + l15) << 9) + koff;
        short8 bf[16];
#pragma unroll
        for (int kk = 0; kk < 16; ++kk) bf[kk] = *(const short8*)(pb + kk * 32);
        f32x4 acc = {0.f, 0.f, 0.f, 0.f};
#pragma unroll
        for (int kk = 0; kk < 16; ++kk)
          acc = __builtin_amdgcn_mfma_f32_16x16x32_bf16(aX[kk], bf[kk], acc, 0, 0, 0);
        const float bb = p.b1[n0 + l15];
#pragma unroll
        for (int i = 0; i < 4; ++i) {
          const short v = (short)f2bf(fmaxf(acc[i] + bb, 0.f));
          h1s[rb + g * 4 + i][n0 + l15] = v;
          if (jh == 0)
            p.h1w[(size_t)(R0 + rb + g * 4 + i) * 256 + n0 + l15] = v;
        }
      }
      {
        const int n0 = cq << 4;
        const short* pb = p.wsl + 131072 + ((size_t)(n0 + l15) << 9) + koff;
        short8 bf[16];
#pragma unroll
        for (int kk = 0; kk < 16; ++kk) bf[kk] = *(const short8*)(pb + kk * 32);
        f32x4 acc = {0.f, 0.f, 0.f, 0.f};
#pragma unroll
        for (int kk = 0; kk < 16; ++kk)
          acc = __builtin_amdgcn_mfma_f32_16x16x32_bf16(aX[kk], bf[kk], acc, 0, 0, 0);
#pragma unroll
        for (int i = 0; i < 4; ++i) hs[rb + g * 4 + i][n0 + l15] = acc[i];
      }
    }
  }
  __syncthreads();   // h1s, hs ready; xs consumed -> ring free

  // ---- stage C: wave (mh,kh,nq2) streams its 64 4KB chunks (k-half x
  //      j-slice nqg) through a PRIVATE 3-deep ring; r14 pipeline verbatim ----
  {
    const int kg0 = kh << 5;
    const int jg  = (nqg << 4) + l15;
    const int mb  = mh << 5;
    short8 aH0[8], aH1[8];
#pragma unroll
    for (int kk = 0; kk < 8; ++kk) {
      aH0[kk] = *(const short8*)&h1s[mb + l15][kk * 32 + koff];
      aH1[kk] = *(const short8*)&h1s[mb + 16 + l15][kk * 32 + koff];
    }
    float t0[4] = {0.f, 0.f, 0.f, 0.f}, t1[4] = {0.f, 0.f, 0.f, 0.f};
    // b2 einsum-bias part for this k-half
    {
      const float* pb2 = p.b2 + D_N + jg;
#pragma unroll 4
      for (int k = kg0; k < kg0 + 32; ++k) {
        const float b2v = pb2[k << 6];
#pragma unroll
        for (int i = 0; i < 4; ++i) {
          t0[i] += hs[mb + g * 4 + i][k] * b2v;
          t1[i] += hs[mb + 16 + g * 4 + i][k] * b2v;
        }
      }
    }

    const short* W2p = p.wsl + 163840;
    short* ringw = &ring[w][0][0];
    const int cbase = kg0 << 1;

    asm volatile("s_waitcnt vmcnt(0)" ::: "memory");
    stage_chunk(W2p, ringw,        cbase + 0, nqg, lane);
    stage_chunk(W2p, ringw + 2048, cbase + 1, nqg, lane);
    stage_chunk(W2p, ringw + 4096, cbase + 2, nqg, lane);

#pragma unroll 1
    for (int kgi = 0; kgi < 32; ++kgi) {
      const int kg = kg0 + kgi;
      f32x4 s0 = {0.f, 0.f, 0.f, 0.f}, s1 = {0.f, 0.f, 0.f, 0.f};
      // ---- phase 0: chunk c = 2*kgi (t-half 0) ----
      {
        const int slot = (2 * kgi) % 3;
        if (kgi < 31) asm volatile("s_waitcnt vmcnt(8)" ::: "memory");
        else          asm volatile("s_waitcnt vmcnt(4)" ::: "memory");
        const short* rb = ringw + slot * 2048 + (lane << 3);
        short8 bf[4];
#pragma unroll
        for (int kk = 0; kk < 4; ++kk) bf[kk] = *(const short8*)(rb + (kk << 9));
        asm volatile("s_waitcnt lgkmcnt(0)" ::: "memory");
        __builtin_amdgcn_sched_barrier(0);
        if (kgi <= 30)
          stage_chunk(W2p, ringw + slot * 2048, cbase + 2 * kgi + 3, nqg, lane);
#pragma unroll
        for (int kk = 0; kk < 4; ++kk) {
          s0 = __builtin_amdgcn_mfma_f32_16x16x32_bf16(aH0[kk], bf[kk], s0, 0, 0, 0);
          s1 = __builtin_amdgcn_mfma_f32_16x16x32_bf16(aH1[kk], bf[kk], s1, 0, 0, 0);
        }
      }
      // ---- phase 1: chunk c = 2*kgi+1 (t-half 1) ----
      {
        const int slot = (2 * kgi + 1) % 3;
        if (kgi < 31) asm volatile("s_waitcnt vmcnt(8)" ::: "memory");
        else          asm volatile("s_waitcnt vmcnt(0)" ::: "memory");
        const short* rb = ringw + slot * 2048 + (lane << 3);
        short8 bf[4];
#pragma unroll
        for (int kk = 0; kk < 4; ++kk) bf[kk] = *(const short8*)(rb + (kk << 9));
        asm volatile("s_waitcnt lgkmcnt(0)" ::: "memory");
        __builtin_amdgcn_sched_barrier(0);
        if (kgi <= 29)
          stage_chunk(W2p, ringw + slot * 2048, cbase + 2 * kgi + 4, nqg, lane);
#pragma unroll
        for (int kk = 0; kk < 4; ++kk) {
          s0 = __builtin_amdgcn_mfma_f32_16x16x32_bf16(aH0[4 + kk], bf[kk], s0, 0, 0, 0);
          s1 = __builtin_amdgcn_mfma_f32_16x16x32_bf16(aH1[4 + kk], bf[kk], s1, 0, 0, 0);
        }
      }
      // ---- fold S fragment with h ----
#pragma unroll
      for (int i = 0; i < 4; ++i) {
        t0[i] += hs[mb + g * 4 + i][kg] * s0[i];
        t1[i] += hs[mb + 16 + g * 4 + i][kg] * s1[i];
      }
    }

    // ---- k-half join via kh=0 wave's ring area, then plain global store ----
    float* tpw = (float*)&ring[w][0][0];
    if (kh == 0) {
#pragma unroll
      for (int i = 0; i < 4; ++i) {
        tpw[(g * 4 + i) * 16 + l15]      = t0[i];
        tpw[(16 + g * 4 + i) * 16 + l15] = t1[i];
      }
    }
    __syncthreads();
    if (kh == 1) {
      const float* tpp = (const float*)&ring[w - 2][0][0];
#pragma unroll
      for (int i = 0; i < 4; ++i) {
        p.tmpf[(size_t)(R0 + mb + g * 4 + i) * 64 + jg] =
            tpp[(g * 4 + i) * 16 + l15] + t0[i];
        p.tmpf[(size_t)(R0 + mb + 16 + g * 4 + i) * 64 + jg] =
            tpp[(16 + g * 4 + i) * 16 + l15] + t1[i];
      }
    }
  }
}

// ============ KD: xnew = relu(tmp@V + h1@W2b + b2[:512])  (r15 verbatim) ====
struct K3Params {
  const short* wsl; const short* h1w; const float* tmpf;
  const float* b2; short* xw;
};
__global__ __launch_bounds__(NT, 1) void k3_proj(K3Params p) {
  const int tid = threadIdx.x;
  const int w = tid >> 6, rh = w >> 2, nq = w & 3;
  const int l15 = tid & 15, g = (tid & 63) >> 4, koff = g * 8;
  const int R0 = blockIdx.x * 32, rbase = rh * 16;
  const short* W2bT = p.wsl + 1212416;
  const short* VT   = p.wsl + 1343488;

  short8 aT[2];
#pragma unroll
  for (int kk = 0; kk < 2; ++kk) {
    short8 t;
#pragma unroll
    for (int e = 0; e < 8; ++e)
      t[e] = (short)f2bf(p.tmpf[(size_t)(R0 + rbase + l15) * 64 + kk * 32 + koff + e]);
    aT[kk] = t;
  }
  short8 aD[8];
#pragma unroll
  for (int kk = 0; kk < 8; ++kk)
    aD[kk] = *(const short8*)&p.h1w[(size_t)(R0 + rbase + l15) * 256 + kk * 32 + koff];

  for (int ti = 0; ti < 8; ++ti) {
    const int n0 = ((ti << 2) + nq) << 4;
    const short* pv = VT + ((size_t)(n0 + l15) << 6) + koff;
    const short* pw = W2bT + ((size_t)(n0 + l15) << 8) + koff;
    short8 bv[2], bw[8];
#pragma unroll
    for (int kk = 0; kk < 2; ++kk) bv[kk] = *(const short8*)(pv + kk * 32);
#pragma unroll
    for (int kk = 0; kk < 8; ++kk) bw[kk] = *(const short8*)(pw + kk * 32);
    f32x4 acc = {0.f, 0.f, 0.f, 0.f};
#pragma unroll
    for (int kk = 0; kk < 2; ++kk)
      acc = __builtin_amdgcn_mfma_f32_16x16x32_bf16(aT[kk], bv[kk], acc, 0, 0, 0);
#pragma unroll
    for (int kk = 0; kk < 8; ++kk)
      acc = __builtin_amdgcn_mfma_f32_16x16x32_bf16(aD[kk], bw[kk], acc, 0, 0, 0);
    const float bb = p.b2[n0 + l15];
#pragma unroll
    for (int i = 0; i < 4; ++i)
      p.xw[(size_t)(R0 + rbase + g * 4 + i) * 512 + n0 + l15] =
          (short)f2bf(fmaxf(acc[i] + bb, 0.f));
  }
}

// ================= K4: out = x @ Wout + bout =================
__global__ __launch_bounds__(NT, 1) void k4_out(const short* xw, const float* Wout,
                                                const float* bout, float* out) {
  const int tid = threadIdx.x;
  const int R0 = blockIdx.x * 32;
  const int r = tid >> 4, cl = tid & 15;
  float acc = 0.f;
  for (int c = cl; c < D_N; c += 16)
    acc = fmaf(bf2f((unsigned short)xw[(size_t)(R0 + r) * 512 + c]), Wout[c], acc);
#pragma unroll
  for (int s = 1; s < 16; s <<= 1) acc += __shfl_xor(acc, s, 64);
  if (cl == 0) out[R0 + r] = acc + bout[0];
}

// ====================== launcher ======================
extern "C" void kernel_launch(void* const* d_in, const int* in_sizes, int n_in,
                              void* d_out, int out_size, void* d_ws, size_t ws_size,
                              hipStream_t stream) {
  (void)in_sizes; (void)n_in; (void)out_size; (void)ws_size;
  PrepParams pp;
  const float* xf = (const float*)d_in[0];
  const float* b1p[3]; const float* b2p[3];
  for (int l = 0; l < 3; ++l) {
    const int base = 1 + l * 6;
    pp.U[l]  = (const float*)d_in[base + 0];
    pp.V[l]  = (const float*)d_in[base + 1];
    pp.W1[l] = (const float*)d_in[base + 2];
    b1p[l]   = (const float*)d_in[base + 3];
    pp.W2[l] = (const float*)d_in[base + 4];
    b2p[l]   = (const float*)d_in[base + 5];
  }
  const float* Wout = (const float*)d_in[19];
  const float* bout = (const float*)d_in[20];
  pp.ws = (short*)d_ws;

  short* wsw  = (short*)d_ws;
  short* h1w  = (short*)((char*)d_ws + OFF_H1);
  float* tmpf = (float*)((char*)d_ws + OFF_TMP);
  short* xw   = (short*)((char*)d_ws + OFF_X);

  hipLaunchKernelGGL(prep_weights, dim3(1024, 15), dim3(256), 0, stream, pp);
  for (int l = 0; l < 3; ++l) {
    CParams pc;
    pc.xf = (l == 0) ? xf : nullptr;
    pc.xb = xw;
    pc.wsl = wsw + (size_t)l * L_ELEMS;
    pc.b1 = b1p[l]; pc.b2 = b2p[l];
    pc.h1w = h1w; pc.tmpf = tmpf;
    hipLaunchKernelGGL(apg_c, dim3(B_N / 32), dim3(NT), 0, stream, pc);

    K3Params p3;
    p3.wsl = wsw + (size_t)l * L_ELEMS;
    p3.h1w = h1w; p3.tmpf = tmpf; p3.b2 = b2p[l]; p3.xw = xw;
    hipLaunchKernelGGL(k3_proj, dim3(B_N / 32), dim3(NT), 0, stream, p3);
  }
  hipLaunchKernelGGL(k4_out, dim3(B_N / 32), dim3(NT), 0, stream,
                     (const short*)xw, Wout, bout, (float*)d_out);
}

// Round 21
// 194.889 us; speedup vs baseline: 1.6135x; 1.6135x over previous
//
#include <hip/hip_runtime.h>

#define B_N 8192
#define D_N 512
#define K_N 64
#define H_N 256
#define SC  4608   // K*K + D
#define R_T 32     // rows per block
#define NT  512    // 8 waves

typedef __attribute__((ext_vector_type(8))) short short8;
typedef __attribute__((ext_vector_type(4))) short short4v;
typedef __attribute__((ext_vector_type(4))) float f32x4;

__device__ __forceinline__ unsigned short f2bf(float f) {
  unsigned int u = __builtin_bit_cast(unsigned int, f);
  u += 0x7fff + ((u >> 16) & 1);      // RNE
  return (unsigned short)(u >> 16);
}
__device__ __forceinline__ float bf2f(unsigned short h) {
  unsigned int u = ((unsigned int)h) << 16;
  return __builtin_bit_cast(float, u);
}

// ---- workspace layout (bf16 elements), per layer ----
// W1T [256][512]  @ 0        (W1T[n][k] = W1[k][n])
// UT  [ 64][512]  @ 131072
// W2C [chunks]    @ 163840   : 4KB chunks, chunk id c = (kg*2+th)*4 + nq:
//                  elem = c*2048 + kk*512 + lane*8 + te   (lane = g*16+l15)
//                  value = W2[t][512 + 64*kg + nq*16 + l15],
//                  t = th*128 + kk*32 + g*8 + te
// W2bT[ 512][256] @ 1212416  (W2bT[n][t] = W2[t][n])
// VT  [ 512][ 64] @ 1343488
#define L_ELEMS 1376256

struct PrepParams {
  const float* W1[3]; const float* U[3]; const float* W2[3]; const float* V[3];
  short* ws;
};

__global__ __launch_bounds__(256) void prep_weights(PrepParams p) {
  const int y = blockIdx.y;           // 0..14
  const int l = y / 5, m = y - 5 * l;
  short* wsl = p.ws + (size_t)l * L_ELEMS;
  if (m == 2) {                       // W2C chunked layout
    const float* in = p.W2[l];
    short* out = wsl + 163840;
    const long total = 1048576;
    for (long e = (long)blockIdx.x * 256 + threadIdx.x; e < total;
         e += (long)gridDim.x * 256) {
      const int te   = (int)(e & 7);
      const int lane = (int)((e >> 3) & 63);
      const int kk   = (int)((e >> 9) & 3);
      const int nq   = (int)((e >> 11) & 3);
      const int h2   = (int)((e >> 13) & 1);
      const int kg   = (int)(e >> 14);
      const int g    = lane >> 4;
      const int l15  = lane & 15;
      const int t    = h2 * 128 + kk * 32 + g * 8 + te;
      out[e] = (short)f2bf(in[(size_t)t * SC + 512 + 64 * kg + nq * 16 + l15]);
    }
    return;
  }
  const float* in; short* out; int K, istride, ioff, kshift;
  switch (m) {
    case 0: in = p.W1[l]; out = wsl;           K = 512; istride = 256;  ioff = 0; kshift = 9; break;
    case 1: in = p.U[l];  out = wsl + 131072;  K = 512; istride = 64;   ioff = 0; kshift = 9; break;
    case 3: in = p.W2[l]; out = wsl + 1212416; K = 256; istride = 4608; ioff = 0; kshift = 8; break;
    default:in = p.V[l];  out = wsl + 1343488; K = 64;  istride = 512;  ioff = 0; kshift = 6; break;
  }
  const long total = (long)K * ((m == 0) ? 256 : (m == 1) ? 64 : 512);
  for (long e = (long)blockIdx.x * 256 + threadIdx.x; e < total;
       e += (long)gridDim.x * 256) {
    const int k = (int)(e & (K - 1));
    const int n = (int)(e >> kshift);
    out[e] = (short)f2bf(in[(size_t)k * istride + ioff + n]);
  }
}

struct Params {
  const float* x;
  const float* b1[3];
  const float* b2[3];
  const float* Wout;
  const float* bout;
  const short* ws;
  float* out;
};

#define XP 520   // xs pitch in shorts
#define HP 264
#define TP 72

// stage one 4KB chunk into this wave's private ring slot (4 x 16B per lane)
__device__ __forceinline__ void stage_chunk(const short* W2p, short* slotp,
                                            int cglob, int nq, int lane) {
  const short* gp = W2p + (((size_t)cglob * 4 + nq) << 11) + (lane << 3);
#pragma unroll
  for (int i = 0; i < 4; ++i) {
    __builtin_amdgcn_global_load_lds(
        (const __attribute__((address_space(1))) void*)(gp + (i << 9)),
        (__attribute__((address_space(3))) void*)(slotp + (i << 9)), 16, 0, 0);
  }
}

#define DS_READ4(dst, SLOT)                                                   \
  do {                                                                        \
    const short* rb_ = ringw + (SLOT) * 2048 + (lane << 3);                   \
    dst[0] = *(const short8*)(rb_);                                           \
    dst[1] = *(const short8*)(rb_ + 512);                                     \
    dst[2] = *(const short8*)(rb_ + 1024);                                    \
    dst[3] = *(const short8*)(rb_ + 1536);                                    \
  } while (0)

#define MFMA_TH0(bf)                                                          \
  do {                                                                        \
    f32x4 z_ = {0.f, 0.f, 0.f, 0.f};                                          \
    s0 = z_; s1 = z_;                                                         \
    _Pragma("unroll")                                                         \
    for (int kk = 0; kk < 4; ++kk) {                                          \
      s0 = __builtin_amdgcn_mfma_f32_16x16x32_bf16(aH0[kk], bf[kk], s0, 0, 0, 0); \
      s1 = __builtin_amdgcn_mfma_f32_16x16x32_bf16(aH1[kk], bf[kk], s1, 0, 0, 0); \
    }                                                                         \
  } while (0)

#define MFMA_TH1_FOLD(bf, KG)                                                 \
  do {                                                                        \
    _Pragma("unroll")                                                         \
    for (int kk = 0; kk < 4; ++kk) {                                          \
      s0 = __builtin_amdgcn_mfma_f32_16x16x32_bf16(aH0[4 + kk], bf[kk], s0, 0, 0, 0); \
      s1 = __builtin_amdgcn_mfma_f32_16x16x32_bf16(aH1[4 + kk], bf[kk], s1, 0, 0, 0); \
    }                                                                         \
    _Pragma("unroll")                                                         \
    for (int i = 0; i < 4; ++i) {                                             \
      t0[i] += hs[g * 4 + i][(KG)] * s0[i];                                   \
      t1[i] += hs[16 + g * 4 + i][(KG)] * s1[i];                              \
    }                                                                         \
  } while (0)

__global__ __launch_bounds__(NT, 1) void apg_mfma(Params p) {
  __shared__ __attribute__((aligned(16))) short ring[8][4][2048]; // 128 KB per-wave private rings
  __shared__ short h1s[R_T][HP];    // 16.9 KB
  __shared__ short tmps[R_T][TP];   //  4.6 KB
  __shared__ float hs[R_T][68];     //  8.7 KB (pad 68: conflict-free)
  // x tile aliases ring; stage-C k-half join also uses dead ring space.
  short (*xs)[XP] = (short (*)[XP]) & ring[0][0][0];

  const int tid  = threadIdx.x;
  const int row0 = blockIdx.x * R_T;
  const int w    = tid >> 6;         // wave 0..7
  const int lane = tid & 63;
  const int l15  = tid & 15;
  const int g    = (tid & 63) >> 4;  // 0..3
  const int koff = g * 8;
  const int rh   = w >> 2;           // row-half for stages A/B/D
  const int nq   = w & 3;            // col-quarter
  const int rbase = rh * 16;

  // ---- load x tile -> bf16 LDS ----
  {
    const float4* xg = (const float4*)(p.x + (size_t)row0 * D_N);
    for (int i = tid; i < R_T * D_N / 4; i += NT) {
      float4 v = xg[i];
      const int r = i >> 7;
      const int c = (i & 127) << 2;
      short4v s4 = { (short)f2bf(v.x), (short)f2bf(v.y), (short)f2bf(v.z), (short)f2bf(v.w) };
      *(short4v*)&xs[r][c] = s4;
    }
  }
  __syncthreads();

  for (int l = 0; l < 3; ++l) {
    const short* wsl  = p.ws + (size_t)l * L_ELEMS;
    const short* W1T  = wsl;
    const short* UT   = wsl + 131072;
    const short* W2p  = wsl + 163840;
    const short* W2bT = wsl + 1212416;
    const short* VT   = wsl + 1343488;
    const float* b1 = p.b1[l];
    const float* b2 = p.b2[l];

    // ---- A-operand x fragments (rows rbase..rbase+16), for stages A+B ----
    short8 aX[16];
#pragma unroll
    for (int kk = 0; kk < 16; ++kk)
      aX[kk] = *(const short8*)&xs[rbase + l15][kk * 32 + koff];

    // ---- stage A: h1 = relu(x @ W1 + b1); wave -> 4 n-frags of its row-half ----
    for (int nf = 0; nf < 4; ++nf) {
      const int n0 = ((nq << 2) + nf) << 4;
      const short* pb = W1T + ((size_t)(n0 + l15) << 9) + koff;
      short8 bf[16];
#pragma unroll
      for (int kk = 0; kk < 16; ++kk) bf[kk] = *(const short8*)(pb + kk * 32);
      f32x4 acc = {0.f, 0.f, 0.f, 0.f};
#pragma unroll
      for (int kk = 0; kk < 16; ++kk)
        acc = __builtin_amdgcn_mfma_f32_16x16x32_bf16(aX[kk], bf[kk], acc, 0, 0, 0);
      const float bb = b1[n0 + l15];
#pragma unroll
      for (int i = 0; i < 4; ++i)
        h1s[rbase + g * 4 + i][n0 + l15] = (short)f2bf(fmaxf(acc[i] + bb, 0.f));
    }

    // ---- stage B: h = x @ U (f32); wave -> n-frag nq, its row-half ----
    {
      const int n0 = nq << 4;
      const short* pb = UT + ((size_t)(n0 + l15) << 9) + koff;
      short8 bf[16];
#pragma unroll
      for (int kk = 0; kk < 16; ++kk) bf[kk] = *(const short8*)(pb + kk * 32);
      f32x4 acc = {0.f, 0.f, 0.f, 0.f};
#pragma unroll
      for (int kk = 0; kk < 16; ++kk)
        acc = __builtin_amdgcn_mfma_f32_16x16x32_bf16(aX[kk], bf[kk], acc, 0, 0, 0);
#pragma unroll
      for (int i = 0; i < 4; ++i) hs[rbase + g * 4 + i][n0 + l15] = acc[i];
    }
    __syncthreads();   // h1s, hs ready; xs consumed -> ring free

    // ---- stage C: tmp[r][j] = sum_k h[r,k] * (h1@W2S + b2S)[r, 64k+j] ----
    // Wave (kh,nq): 64 4KB chunks through a PRIVATE 4-deep ring.
    // Phase c: vmcnt(8) -> issue ds_read of chunk c+1 -> lgkmcnt(4)
    // (waits only prev phase's reads) -> MFMA chunk c -> refill slot(c&3).
    {
      const int kh  = w >> 2;
      const int kg0 = kh << 5;
      const int nl  = (nq << 4) + l15;
      short8 aH0[8], aH1[8];
#pragma unroll
      for (int kk = 0; kk < 8; ++kk) {
        aH0[kk] = *(const short8*)&h1s[l15][kk * 32 + koff];
        aH1[kk] = *(const short8*)&h1s[16 + l15][kk * 32 + koff];
      }
      float t0[4] = {0.f, 0.f, 0.f, 0.f}, t1[4] = {0.f, 0.f, 0.f, 0.f};
      // b2 einsum-bias part for this k-half
      {
        const float* pb2 = b2 + D_N + nl;
#pragma unroll 4
        for (int k = kg0; k < kg0 + 32; ++k) {
          const float b2v = pb2[k << 6];
#pragma unroll
          for (int i = 0; i < 4; ++i) {
            t0[i] += hs[g * 4 + i][k] * b2v;
            t1[i] += hs[16 + g * 4 + i][k] * b2v;
          }
        }
      }

      short* ringw = &ring[w][0][0];
      const int cbase = kg0 << 1;

      asm volatile("s_waitcnt vmcnt(0)" ::: "memory");
      stage_chunk(W2p, ringw,        cbase + 0, nq, lane);
      stage_chunk(W2p, ringw + 2048, cbase + 1, nq, lane);
      stage_chunk(W2p, ringw + 4096, cbase + 2, nq, lane);
      stage_chunk(W2p, ringw + 6144, cbase + 3, nq, lane);
      asm volatile("s_waitcnt vmcnt(12)" ::: "memory");   // chunk 0 landed
      short8 bfA[4], bfB[4];
      DS_READ4(bfA, 0);
      f32x4 s0, s1;

#pragma unroll 1
      for (int it = 0; it < 15; ++it) {
        const int c0 = it << 2;              // phases c0..c0+3  (c0..59)
        // ---- phase c0 (th=0, cur=bfA slot0); read c0+1; refill slot0 ----
        asm volatile("s_waitcnt vmcnt(8)" ::: "memory");
        DS_READ4(bfB, 1);
        asm volatile("s_waitcnt lgkmcnt(4)" ::: "memory");
        __builtin_amdgcn_sched_barrier(0);
        MFMA_TH0(bfA);
        stage_chunk(W2p, ringw,        cbase + c0 + 4, nq, lane);
        // ---- phase c0+1 (th=1, cur=bfB slot1); read c0+2; refill slot1 ----
        asm volatile("s_waitcnt vmcnt(8)" ::: "memory");
        DS_READ4(bfA, 2);
        asm volatile("s_waitcnt lgkmcnt(4)" ::: "memory");
        __builtin_amdgcn_sched_barrier(0);
        MFMA_TH1_FOLD(bfB, kg0 + 2 * it);
        stage_chunk(W2p, ringw + 2048, cbase + c0 + 5, nq, lane);
        // ---- phase c0+2 (th=0, cur=bfA slot2); read c0+3; refill slot2 ----
        asm volatile("s_waitcnt vmcnt(8)" ::: "memory");
        DS_READ4(bfB, 3);
        asm volatile("s_waitcnt lgkmcnt(4)" ::: "memory");
        __builtin_amdgcn_sched_barrier(0);
        MFMA_TH0(bfA);
        stage_chunk(W2p, ringw + 4096, cbase + c0 + 6, nq, lane);
        // ---- phase c0+3 (th=1, cur=bfB slot3); read c0+4; refill slot3 ----
        asm volatile("s_waitcnt vmcnt(8)" ::: "memory");
        DS_READ4(bfA, 0);
        asm volatile("s_waitcnt lgkmcnt(4)" ::: "memory");
        __builtin_amdgcn_sched_barrier(0);
        MFMA_TH1_FOLD(bfB, kg0 + 2 * it + 1);
        stage_chunk(W2p, ringw + 6144, cbase + c0 + 7, nq, lane);
      }
      // ---- tail phases 60..63 (no more refills) ----
      // phase 60 (th=0, cur=bfA=c60); read 61
      asm volatile("s_waitcnt vmcnt(8)" ::: "memory");
      DS_READ4(bfB, 1);
      asm volatile("s_waitcnt lgkmcnt(4)" ::: "memory");
      __builtin_amdgcn_sched_barrier(0);
      MFMA_TH0(bfA);
      // phase 61 (th=1, cur=bfB); read 62
      asm volatile("s_waitcnt vmcnt(4)" ::: "memory");
      DS_READ4(bfA, 2);
      asm volatile("s_waitcnt lgkmcnt(4)" ::: "memory");
      __builtin_amdgcn_sched_barrier(0);
      MFMA_TH1_FOLD(bfB, kg0 + 30);
      // phase 62 (th=0, cur=bfA=c62); read 63
      asm volatile("s_waitcnt vmcnt(0)" ::: "memory");
      DS_READ4(bfB, 3);
      asm volatile("s_waitcnt lgkmcnt(4)" ::: "memory");
      __builtin_amdgcn_sched_barrier(0);
      MFMA_TH0(bfA);
      // phase 63 (th=1, cur=bfB=c63)
      asm volatile("s_waitcnt lgkmcnt(0)" ::: "memory");
      __builtin_amdgcn_sched_barrier(0);
      MFMA_TH1_FOLD(bfB, kg0 + 31);

      // ---- k-half join: kh0 wave writes f32 partials into its own (dead)
      //      ring region; kh1 wave (w-4) adds and stores bf16 to tmps ----
      float* tpw = (float*)&ring[w][0][0];
      if (kh == 0) {
#pragma unroll
        for (int i = 0; i < 4; ++i) {
          tpw[(g * 4 + i) * 16 + l15]        = t0[i];
          tpw[(16 + g * 4 + i) * 16 + l15]   = t1[i];
        }
      }
      __syncthreads();
      if (kh == 1) {
        const float* tpp = (const float*)&ring[w - 4][0][0];
#pragma unroll
        for (int i = 0; i < 4; ++i) {
          tmps[g * 4 + i][nl] =
              (short)f2bf(tpp[(g * 4 + i) * 16 + l15] + t0[i]);
          tmps[16 + g * 4 + i][nl] =
              (short)f2bf(tpp[(16 + g * 4 + i) * 16 + l15] + t1[i]);
        }
      }
    }
    __syncthreads();

    // ---- stage D: xnew = relu(tmp@V + h1@W2b + b2[:512]) -> xs (ring area) ----
    {
      short8 aT[2], aD[8];
#pragma unroll
      for (int kk = 0; kk < 2; ++kk)
        aT[kk] = *(const short8*)&tmps[rbase + l15][kk * 32 + koff];
#pragma unroll
      for (int kk = 0; kk < 8; ++kk)
        aD[kk] = *(const short8*)&h1s[rbase + l15][kk * 32 + koff];
      for (int ti = 0; ti < 8; ++ti) {
        const int n0 = ((ti << 2) + nq) << 4;
        const short* pv = VT + ((size_t)(n0 + l15) << 6) + koff;
        const short* pw = W2bT + ((size_t)(n0 + l15) << 8) + koff;
        short8 bv[2], bw[8];
#pragma unroll
        for (int kk = 0; kk < 2; ++kk) bv[kk] = *(const short8*)(pv + kk * 32);
#pragma unroll
        for (int kk = 0; kk < 8; ++kk) bw[kk] = *(const short8*)(pw + kk * 32);
        f32x4 acc = {0.f, 0.f, 0.f, 0.f};
#pragma unroll
        for (int kk = 0; kk < 2; ++kk)
          acc = __builtin_amdgcn_mfma_f32_16x16x32_bf16(aT[kk], bv[kk], acc, 0, 0, 0);
#pragma unroll
        for (int kk = 0; kk < 8; ++kk)
          acc = __builtin_amdgcn_mfma_f32_16x16x32_bf16(aD[kk], bw[kk], acc, 0, 0, 0);
        const float bb = b2[n0 + l15];
#pragma unroll
        for (int i = 0; i < 4; ++i)
          xs[rbase + g * 4 + i][n0 + l15] = (short)f2bf(fmaxf(acc[i] + bb, 0.f));
      }
    }
    __syncthreads();
  }

  // ---- out = x @ Wout + bout ----
  {
    const int r  = tid >> 4;
    const int cl = tid & 15;
    float acc = 0.f;
    for (int c = cl; c < D_N; c += 16)
      acc = fmaf(bf2f((unsigned short)xs[r][c]), p.Wout[c], acc);
#pragma unroll
    for (int s = 1; s < 16; s <<= 1) acc += __shfl_xor(acc, s, 64);
    if (cl == 0) p.out[row0 + r] = acc + p.bout[0];
  }
}

extern "C" void kernel_launch(void* const* d_in, const int* in_sizes, int n_in,
                              void* d_out, int out_size, void* d_ws, size_t ws_size,
                              hipStream_t stream) {
  (void)in_sizes; (void)n_in; (void)ws_size; (void)out_size;
  PrepParams pp;
  Params p;
  p.x = (const float*)d_in[0];
  for (int l = 0; l < 3; ++l) {
    const int base = 1 + l * 6;
    pp.U[l]  = (const float*)d_in[base + 0];
    pp.V[l]  = (const float*)d_in[base + 1];
    pp.W1[l] = (const float*)d_in[base + 2];
    p.b1[l]  = (const float*)d_in[base + 3];
    pp.W2[l] = (const float*)d_in[base + 4];
    p.b2[l]  = (const float*)d_in[base + 5];
  }
  p.Wout = (const float*)d_in[19];
  p.bout = (const float*)d_in[20];
  p.ws   = (const short*)d_ws;
  p.out  = (float*)d_out;
  pp.ws  = (short*)d_ws;

  hipLaunchKernelGGL(prep_weights, dim3(1024, 15), dim3(256), 0, stream, pp);
  hipLaunchKernelGGL(apg_mfma, dim3(B_N / R_T), dim3(NT), 0, stream, p);
}